// Round 4
// baseline (4886.885 us; speedup 1.0000x reference)
//
#include <hip/hip_runtime.h>

// ---------------------------------------------------------------------------
// MDGRU fused implementation, MI355X (gfx950)
//   B=64, T=2048, D=256, U=256, 3U=768
//   Kernel 1: proj[b][t][0:768] = X[b][t][:] @ kernel + bias   (f16 in d_ws)
//   Kernel 2: per-batch persistent GRU scan, ALL weights register-resident.
//     Round-3 lesson: allocator never grants >128 VGPR/thread regardless of
//     waves_per_eu/launch_bounds hints -> design UNDER the 128 cap instead.
//     64 blocks x 1024 threads (16 waves, 4/SIMD, default 128-VGPR point):
//       phase1: thread(col1=tid>>1, kh1=tid&1) owns K-HALF of U{z,r}[:,col1]
//               = 64 half2 regs; combine via __shfl_xor(1)
//       phase2: thread(colh=tid>>2, kq=tid&3) owns K-QUARTER of Uh[:,colh]
//               = 32 half2 regs; combine via __shfl_xor(1), __shfl_xor(2)
//     96 weight regs + ~25 temps < 128 -> no spill (the experiment).
// ---------------------------------------------------------------------------

typedef _Float16 half2_t __attribute__((ext_vector_type(2)));
typedef _Float16 half8_t __attribute__((ext_vector_type(8)));
typedef float    float4_t __attribute__((ext_vector_type(4)));

#define T_LEN 2048
#define B_SZ  64
#define D_IN  256
#define N3    768   // 3*U
#define U_SZ  256

// extract half2 p (p=0..3) from a half8
#define H2(v, p) __builtin_shufflevector((v), (v), 2*(p), 2*(p)+1)

__device__ __forceinline__ float fdot2f(half2_t a, half2_t b, float c) {
#if __has_builtin(__builtin_amdgcn_fdot2)
    return __builtin_amdgcn_fdot2(a, b, c, false);
#else
    return c + (float)a[0]*(float)b[0] + (float)a[1]*(float)b[1];
#endif
}

__device__ __forceinline__ float fast_sigmoid(float s) {
    return __builtin_amdgcn_rcpf(1.0f + __builtin_amdgcn_exp2f(-1.44269504f * s));
}
__device__ __forceinline__ float fast_tanh(float s) {
    return 1.0f - 2.0f * __builtin_amdgcn_rcpf(1.0f + __builtin_amdgcn_exp2f(2.88539008f * s));
}

// ---------------------------------------------------------------------------
// Kernel 1: proj GEMM (unchanged, known-good: ~830 us).
// ---------------------------------------------------------------------------
#define GA_LD 264
#define NT_N  16          // 768/48
#define MT_M  2048        // 131072/64

__global__ __launch_bounds__(256) void proj_gemm(
    const float* __restrict__ X, const float* __restrict__ W,
    const float* __restrict__ bias, _Float16* __restrict__ proj)
{
    __shared__ __align__(16) _Float16 Ah[64 * GA_LD];   // [row][k]
    __shared__ __align__(16) _Float16 Wh[48 * GA_LD];   // [col][k]

    unsigned bid = blockIdx.x;
    unsigned idx = bid >> 3;
    unsigned mt  = (bid & 7) * (MT_M / 8) + (idx >> 4);
    unsigned nt  = idx & (NT_N - 1);
    int m0 = mt * 64, n0 = nt * 48;
    int tid = threadIdx.x;

    {
        int r = tid >> 6;
        int k = (tid & 63) * 4;
        #pragma unroll
        for (int i = 0; i < 16; ++i) {
            int row = i * 4 + r;
            float4_t v = *(const float4_t*)(X + (size_t)(m0 + row) * D_IN + k);
            _Float16* p = Ah + row * GA_LD + k;
            p[0] = (_Float16)v.x; p[1] = (_Float16)v.y;
            p[2] = (_Float16)v.z; p[3] = (_Float16)v.w;
        }
    }
    {
        int c  = tid & 63;
        int kk = tid >> 6;
        if (c < 48) {
            #pragma unroll 4
            for (int i = 0; i < 64; ++i) {
                int krow = i * 4 + kk;
                Wh[c * GA_LD + krow] = (_Float16)W[(size_t)krow * N3 + n0 + c];
            }
        }
    }
    __syncthreads();

    int r0 = (tid >> 4) << 2;
    int c  = tid & 15;
    float acc[4][3];
    #pragma unroll
    for (int rr = 0; rr < 4; ++rr)
        #pragma unroll
        for (int cc = 0; cc < 3; ++cc) acc[rr][cc] = 0.0f;

    for (int j = 0; j < 32; ++j) {
        half8_t av[4], wv[3];
        #pragma unroll
        for (int rr = 0; rr < 4; ++rr)
            av[rr] = *(const half8_t*)(Ah + (r0 + rr) * GA_LD + j * 8);
        #pragma unroll
        for (int cc = 0; cc < 3; ++cc)
            wv[cc] = *(const half8_t*)(Wh + (c + 16 * cc) * GA_LD + j * 8);
        #pragma unroll
        for (int rr = 0; rr < 4; ++rr)
            #pragma unroll
            for (int cc = 0; cc < 3; ++cc) {
                acc[rr][cc] = fdot2f(H2(av[rr],0), H2(wv[cc],0), acc[rr][cc]);
                acc[rr][cc] = fdot2f(H2(av[rr],1), H2(wv[cc],1), acc[rr][cc]);
                acc[rr][cc] = fdot2f(H2(av[rr],2), H2(wv[cc],2), acc[rr][cc]);
                acc[rr][cc] = fdot2f(H2(av[rr],3), H2(wv[cc],3), acc[rr][cc]);
            }
    }

    float bv[3];
    #pragma unroll
    for (int cc = 0; cc < 3; ++cc) bv[cc] = bias[n0 + c + 16 * cc];
    #pragma unroll
    for (int rr = 0; rr < 4; ++rr)
        #pragma unroll
        for (int cc = 0; cc < 3; ++cc)
            proj[(size_t)(m0 + r0 + rr) * N3 + (n0 + c + 16 * cc)] =
                (_Float16)(acc[rr][cc] + bv[cc]);
}

// ---------------------------------------------------------------------------
// Kernel 2: persistent GRU scan, 64 blocks x 1024 threads.
// ---------------------------------------------------------------------------
__global__ __launch_bounds__(1024) void gru_scan(
    const float* __restrict__ RK, const _Float16* __restrict__ proj,
    float* __restrict__ out)
{
    __shared__ __align__(16) _Float16 aH[U_SZ];    // f16 mirror of state
    __shared__ __align__(16) _Float16 raH[U_SZ];   // f16 r*a
    __shared__ float zS[U_SZ];
    __shared__ float aF[U_SZ];                     // fp32 state (authoritative)

    const int b    = blockIdx.x;
    const int tid  = threadIdx.x;
    const int col1 = tid >> 1;      // [0,512): z cols 0-255, r cols 256-511
    const int kh1  = tid & 1;       // phase-1 K-half
    const int colh = tid >> 2;      // [0,256): h column
    const int kq   = tid & 3;       // phase-2 K-quarter

    // ---- phase-1 weights: K-half of U{z|r}[:,col1], 64 packed half2 VGPRs
    half2_t wA[64];
    {
        const float* wp = RK + (size_t)(kh1 * 128) * N3 + col1;
        #pragma unroll
        for (int k2 = 0; k2 < 64; ++k2) {
            half2_t h;
            h[0] = (_Float16)wp[(size_t)(2 * k2)     * N3];
            h[1] = (_Float16)wp[(size_t)(2 * k2 + 1) * N3];
            wA[k2] = h;
        }
    }
    // ---- phase-2 weights: K-quarter of Uh[:,colh], 32 packed half2 VGPRs
    half2_t wB[32];
    {
        const float* wq = RK + (size_t)(kq * 64) * N3 + 512 + colh;
        #pragma unroll
        for (int k2 = 0; k2 < 32; ++k2) {
            half2_t h;
            h[0] = (_Float16)wq[(size_t)(2 * k2)     * N3];
            h[1] = (_Float16)wq[(size_t)(2 * k2 + 1) * N3];
            wB[k2] = h;
        }
    }

    if (tid < U_SZ) { aF[tid] = 0.0f; aH[tid] = (_Float16)0.0f; }

    // x streams: phase1 proj[b][t][col1], phase2 proj[b][t][512+colh]
    const _Float16* px1 = proj + ((size_t)b * T_LEN) * N3 + col1;
    const _Float16* px2 = proj + ((size_t)b * T_LEN) * N3 + 512 + colh;
    float x1 = (float)px1[0];
    float x2 = (float)px2[0];
    __syncthreads();

    for (int t = 0; t < T_LEN; ++t) {
        const float x1c = x1, x2c = x2;
        if (t + 1 < T_LEN) {
            x1 = (float)px1[(size_t)(t + 1) * N3];
            x2 = (float)px2[(size_t)(t + 1) * N3];
        }

        // ---- phase 1: z,r = sigmoid(a @ U{z,r} + x)   (all 16 waves)
        {
            float a0 = 0.f, a1 = 0.f;
            const _Float16* abase = aH + (kh1 << 7);
            #pragma unroll
            for (int j = 0; j < 16; ++j) {
                half8_t av = *(const half8_t*)(abase + j * 8);   // broadcast
                a0 = fdot2f(H2(av,0), wA[4*j+0], a0);
                a1 = fdot2f(H2(av,1), wA[4*j+1], a1);
                a0 = fdot2f(H2(av,2), wA[4*j+2], a0);
                a1 = fdot2f(H2(av,3), wA[4*j+3], a1);
            }
            float hs = a0 + a1;
            hs += __shfl_xor(hs, 1, 64);                 // combine K-halves
            if (kh1 == 0) {
                float sig = fast_sigmoid(hs + x1c);
                if (col1 < U_SZ) zS[col1] = sig;         // wave-uniform branch
                else raH[col1 - U_SZ] = (_Float16)(sig * aF[col1 - U_SZ]);
            }
        }
        __syncthreads();

        // ---- phase 2: h = tanh((r*a) @ Uh + x); a' = z*a + (1-z)*h
        {
            float b0 = 0.f, b1 = 0.f;
            const _Float16* rbase = raH + (kq << 6);
            #pragma unroll
            for (int j = 0; j < 8; ++j) {
                half8_t rv = *(const half8_t*)(rbase + j * 8);   // broadcast
                b0 = fdot2f(H2(rv,0), wB[4*j+0], b0);
                b1 = fdot2f(H2(rv,1), wB[4*j+1], b1);
                b0 = fdot2f(H2(rv,2), wB[4*j+2], b0);
                b1 = fdot2f(H2(rv,3), wB[4*j+3], b1);
            }
            float hs = b0 + b1;
            hs += __shfl_xor(hs, 1, 64);                 // combine K-quarters
            hs += __shfl_xor(hs, 2, 64);
            if (kq == 0) {
                float h  = fast_tanh(hs + x2c);
                float z  = zS[colh];
                float an = z * aF[colh] + (1.0f - z) * h;
                aF[colh] = an;
                aH[colh] = (_Float16)an;
            }
        }
        __syncthreads();
    }

    if (tid < U_SZ) out[(size_t)b * U_SZ + tid] = aF[tid];
}

// ---------------------------------------------------------------------------
extern "C" void kernel_launch(void* const* d_in, const int* in_sizes, int n_in,
                              void* d_out, int out_size, void* d_ws, size_t ws_size,
                              hipStream_t stream)
{
    const float* X    = (const float*)d_in[0];   // (64,2048,256)
    const float* W    = (const float*)d_in[1];   // (256,768)
    const float* RK   = (const float*)d_in[2];   // (256,768)
    const float* bias = (const float*)d_in[3];   // (768,)
    _Float16* proj = (_Float16*)d_ws;            // 131072*768*2 = 201.3 MB

    proj_gemm<<<MT_M * NT_N, 256, 0, stream>>>(X, W, bias, proj);
    gru_scan<<<B_SZ, 1024, 0, stream>>>(RK, proj, (float*)d_out);
}

// Round 6
// 3969.505 us; speedup vs baseline: 1.2311x; 1.2311x over previous
//
#include <hip/hip_runtime.h>

// ---------------------------------------------------------------------------
// MDGRU fused implementation, MI355X (gfx950)
//   B=64, T=2048, D=256, U=256, 3U=768
//   Kernel 1: proj[b][t][0:768] = X[b][t][:] @ kernel + bias   (f16 in d_ws)
//   Kernel 2: per-batch persistent GRU scan, ALL weights in named VGPRs.
//
//   Round 2-4 lesson: the AMDGPU regalloc always targets 2 blocks/CU
//   (grants were exactly 1024/waves_per_block: 84@768thr, 128@512thr,
//   64@1024thr) and spilled half the weight set to scratch every time;
//   launch_bounds(,2) and waves_per_eu(2,2) were both ignored.
//   Fix here: (a) LDS-FORCED OCCUPANCY — a 96 KB static pad makes
//   1 block/CU the LDS-bound maximum, so the achievable occupancy is
//   2 waves/SIMD and the pressure target rises to 512/2 = 256 VGPRs;
//   (b) weights are 192 NAMED half2 variables (no arrays -> cannot be
//   demoted to scratch via dynamic indexing, rule #20).
//   Decisive counter check: VGPR_Count must read >= 200 (128 = falsified).
//   (Round 5 was a GPU-acquisition timeout; this is the same experiment.)
// ---------------------------------------------------------------------------

typedef _Float16 half2_t __attribute__((ext_vector_type(2)));
typedef _Float16 half8_t __attribute__((ext_vector_type(8)));
typedef float    float4_t __attribute__((ext_vector_type(4)));

#define T_LEN 2048
#define B_SZ  64
#define D_IN  256
#define N3    768   // 3*U
#define U_SZ  256

// extract half2 p (p=0..3) from a half8
#define H2(v, p) __builtin_shufflevector((v), (v), 2*(p), 2*(p)+1)

__device__ __forceinline__ float fdot2f(half2_t a, half2_t b, float c) {
#if __has_builtin(__builtin_amdgcn_fdot2)
    return __builtin_amdgcn_fdot2(a, b, c, false);
#else
    return c + (float)a[0]*(float)b[0] + (float)a[1]*(float)b[1];
#endif
}

__device__ __forceinline__ float fast_sigmoid(float s) {
    return __builtin_amdgcn_rcpf(1.0f + __builtin_amdgcn_exp2f(-1.44269504f * s));
}
__device__ __forceinline__ float fast_tanh(float s) {
    return 1.0f - 2.0f * __builtin_amdgcn_rcpf(1.0f + __builtin_amdgcn_exp2f(2.88539008f * s));
}

// pack RK[2i][col], RK[2i+1][col] (stride N3 floats) into one half2
__device__ __forceinline__ half2_t ldw(const float* p) {
    half2_t h; h[0] = (_Float16)p[0]; h[1] = (_Float16)p[N3]; return h;
}

// ---------------------------------------------------------------------------
// Kernel 1: proj GEMM (unchanged, known-good: ~830 us).
// ---------------------------------------------------------------------------
#define GA_LD 264
#define NT_N  16          // 768/48
#define MT_M  2048        // 131072/64

__global__ __launch_bounds__(256) void proj_gemm(
    const float* __restrict__ X, const float* __restrict__ W,
    const float* __restrict__ bias, _Float16* __restrict__ proj)
{
    __shared__ __align__(16) _Float16 Ah[64 * GA_LD];   // [row][k]
    __shared__ __align__(16) _Float16 Wh[48 * GA_LD];   // [col][k]

    unsigned bid = blockIdx.x;
    unsigned idx = bid >> 3;
    unsigned mt  = (bid & 7) * (MT_M / 8) + (idx >> 4);
    unsigned nt  = idx & (NT_N - 1);
    int m0 = mt * 64, n0 = nt * 48;
    int tid = threadIdx.x;

    {
        int r = tid >> 6;
        int k = (tid & 63) * 4;
        #pragma unroll
        for (int i = 0; i < 16; ++i) {
            int row = i * 4 + r;
            float4_t v = *(const float4_t*)(X + (size_t)(m0 + row) * D_IN + k);
            _Float16* p = Ah + row * GA_LD + k;
            p[0] = (_Float16)v.x; p[1] = (_Float16)v.y;
            p[2] = (_Float16)v.z; p[3] = (_Float16)v.w;
        }
    }
    {
        int c  = tid & 63;
        int kk = tid >> 6;
        if (c < 48) {
            #pragma unroll 4
            for (int i = 0; i < 64; ++i) {
                int krow = i * 4 + kk;
                Wh[c * GA_LD + krow] = (_Float16)W[(size_t)krow * N3 + n0 + c];
            }
        }
    }
    __syncthreads();

    int r0 = (tid >> 4) << 2;
    int c  = tid & 15;
    float acc[4][3];
    #pragma unroll
    for (int rr = 0; rr < 4; ++rr)
        #pragma unroll
        for (int cc = 0; cc < 3; ++cc) acc[rr][cc] = 0.0f;

    for (int j = 0; j < 32; ++j) {
        half8_t av[4], wv[3];
        #pragma unroll
        for (int rr = 0; rr < 4; ++rr)
            av[rr] = *(const half8_t*)(Ah + (r0 + rr) * GA_LD + j * 8);
        #pragma unroll
        for (int cc = 0; cc < 3; ++cc)
            wv[cc] = *(const half8_t*)(Wh + (c + 16 * cc) * GA_LD + j * 8);
        #pragma unroll
        for (int rr = 0; rr < 4; ++rr)
            #pragma unroll
            for (int cc = 0; cc < 3; ++cc) {
                acc[rr][cc] = fdot2f(H2(av[rr],0), H2(wv[cc],0), acc[rr][cc]);
                acc[rr][cc] = fdot2f(H2(av[rr],1), H2(wv[cc],1), acc[rr][cc]);
                acc[rr][cc] = fdot2f(H2(av[rr],2), H2(wv[cc],2), acc[rr][cc]);
                acc[rr][cc] = fdot2f(H2(av[rr],3), H2(wv[cc],3), acc[rr][cc]);
            }
    }

    float bv[3];
    #pragma unroll
    for (int cc = 0; cc < 3; ++cc) bv[cc] = bias[n0 + c + 16 * cc];
    #pragma unroll
    for (int rr = 0; rr < 4; ++rr)
        #pragma unroll
        for (int cc = 0; cc < 3; ++cc)
            proj[(size_t)(m0 + r0 + rr) * N3 + (n0 + c + 16 * cc)] =
                (_Float16)(acc[rr][cc] + bv[cc]);
}

// ---------------------------------------------------------------------------
// Kernel 2: persistent GRU scan, 64 blocks x 512 threads, 1 block/CU forced
// by a 96 KB LDS pad. Weights: 192 named half2 VGPRs per thread.
//   phase1: thread(g=tid>>8, u=tid&255) owns U{z|r}[:,u]      (wa0..wa127)
//   phase2: thread(hcol=tid>>1, kh=tid&1) owns K-half Uh[:,hcol] (wb0..wb63)
//           partials combined via __shfl_xor(1) (in-wave partner)
// ---------------------------------------------------------------------------
__global__ __launch_bounds__(512)
__attribute__((amdgpu_waves_per_eu(2, 2)))
void gru_scan(
    const float* __restrict__ RK, const _Float16* __restrict__ proj,
    float* __restrict__ out)
{
    // 96 KB pad: 2 blocks would need 202 KB > 160 KB -> 1 block/CU.
    __shared__ float occ_pad[24576];
    __shared__ __align__(16) _Float16 aH[U_SZ];    // f16 mirror of state
    __shared__ __align__(16) _Float16 raH[U_SZ];   // f16 r*a
    __shared__ float zS[U_SZ];
    __shared__ float aF[U_SZ];                     // fp32 state (authoritative)

    const int b    = blockIdx.x;
    const int tid  = threadIdx.x;
    const int g    = tid >> 8;       // 0=z, 1=r (wave-uniform)
    const int u    = tid & 255;
    const int hcol = tid >> 1;       // phase-2 Uh column
    const int kh   = tid & 1;        // phase-2 K-half

    // keep the pad alive (volatile store defeats dead-LDS elimination)
    { volatile float* vp = occ_pad; vp[tid] = 0.0f; }

    // ---- phase-1 weights: U{z|r}[:,u], 128 named half2 regs
    half2_t wa0,wa1,wa2,wa3,wa4,wa5,wa6,wa7,wa8,wa9,wa10,wa11,wa12,wa13,wa14,wa15,
            wa16,wa17,wa18,wa19,wa20,wa21,wa22,wa23,wa24,wa25,wa26,wa27,wa28,wa29,wa30,wa31,
            wa32,wa33,wa34,wa35,wa36,wa37,wa38,wa39,wa40,wa41,wa42,wa43,wa44,wa45,wa46,wa47,
            wa48,wa49,wa50,wa51,wa52,wa53,wa54,wa55,wa56,wa57,wa58,wa59,wa60,wa61,wa62,wa63,
            wa64,wa65,wa66,wa67,wa68,wa69,wa70,wa71,wa72,wa73,wa74,wa75,wa76,wa77,wa78,wa79,
            wa80,wa81,wa82,wa83,wa84,wa85,wa86,wa87,wa88,wa89,wa90,wa91,wa92,wa93,wa94,wa95,
            wa96,wa97,wa98,wa99,wa100,wa101,wa102,wa103,wa104,wa105,wa106,wa107,wa108,wa109,wa110,wa111,
            wa112,wa113,wa114,wa115,wa116,wa117,wa118,wa119,wa120,wa121,wa122,wa123,wa124,wa125,wa126,wa127;
    {
        const float* wp = RK + (size_t)(g << 8) + u;   // RK[k][g*256+u]
        #define LA(i) wa##i = ldw(wp + (size_t)(2*(i)) * N3);
        LA(0) LA(1) LA(2) LA(3) LA(4) LA(5) LA(6) LA(7)
        LA(8) LA(9) LA(10) LA(11) LA(12) LA(13) LA(14) LA(15)
        LA(16) LA(17) LA(18) LA(19) LA(20) LA(21) LA(22) LA(23)
        LA(24) LA(25) LA(26) LA(27) LA(28) LA(29) LA(30) LA(31)
        LA(32) LA(33) LA(34) LA(35) LA(36) LA(37) LA(38) LA(39)
        LA(40) LA(41) LA(42) LA(43) LA(44) LA(45) LA(46) LA(47)
        LA(48) LA(49) LA(50) LA(51) LA(52) LA(53) LA(54) LA(55)
        LA(56) LA(57) LA(58) LA(59) LA(60) LA(61) LA(62) LA(63)
        LA(64) LA(65) LA(66) LA(67) LA(68) LA(69) LA(70) LA(71)
        LA(72) LA(73) LA(74) LA(75) LA(76) LA(77) LA(78) LA(79)
        LA(80) LA(81) LA(82) LA(83) LA(84) LA(85) LA(86) LA(87)
        LA(88) LA(89) LA(90) LA(91) LA(92) LA(93) LA(94) LA(95)
        LA(96) LA(97) LA(98) LA(99) LA(100) LA(101) LA(102) LA(103)
        LA(104) LA(105) LA(106) LA(107) LA(108) LA(109) LA(110) LA(111)
        LA(112) LA(113) LA(114) LA(115) LA(116) LA(117) LA(118) LA(119)
        LA(120) LA(121) LA(122) LA(123) LA(124) LA(125) LA(126) LA(127)
        #undef LA
    }
    // ---- phase-2 weights: K-half of Uh[:,hcol], 64 named half2 regs
    half2_t wb0,wb1,wb2,wb3,wb4,wb5,wb6,wb7,wb8,wb9,wb10,wb11,wb12,wb13,wb14,wb15,
            wb16,wb17,wb18,wb19,wb20,wb21,wb22,wb23,wb24,wb25,wb26,wb27,wb28,wb29,wb30,wb31,
            wb32,wb33,wb34,wb35,wb36,wb37,wb38,wb39,wb40,wb41,wb42,wb43,wb44,wb45,wb46,wb47,
            wb48,wb49,wb50,wb51,wb52,wb53,wb54,wb55,wb56,wb57,wb58,wb59,wb60,wb61,wb62,wb63;
    {
        const float* wq = RK + (size_t)(kh * 128) * N3 + 512 + hcol;
        #define LB(i) wb##i = ldw(wq + (size_t)(2*(i)) * N3);
        LB(0) LB(1) LB(2) LB(3) LB(4) LB(5) LB(6) LB(7)
        LB(8) LB(9) LB(10) LB(11) LB(12) LB(13) LB(14) LB(15)
        LB(16) LB(17) LB(18) LB(19) LB(20) LB(21) LB(22) LB(23)
        LB(24) LB(25) LB(26) LB(27) LB(28) LB(29) LB(30) LB(31)
        LB(32) LB(33) LB(34) LB(35) LB(36) LB(37) LB(38) LB(39)
        LB(40) LB(41) LB(42) LB(43) LB(44) LB(45) LB(46) LB(47)
        LB(48) LB(49) LB(50) LB(51) LB(52) LB(53) LB(54) LB(55)
        LB(56) LB(57) LB(58) LB(59) LB(60) LB(61) LB(62) LB(63)
        #undef LB
    }

    if (tid < U_SZ) { aF[tid] = 0.0f; aH[tid] = (_Float16)0.0f; }

    // x streams: phase1 proj[b][t][g*256+u], phase2 proj[b][t][512+hcol]
    const _Float16* px1 = proj + ((size_t)b * T_LEN) * N3 + (g << 8) + u;
    const _Float16* px2 = proj + ((size_t)b * T_LEN) * N3 + 512 + hcol;
    float x1 = (float)px1[0];
    float x2 = (float)px2[0];
    __syncthreads();

    for (int t = 0; t < T_LEN; ++t) {
        const float x1c = x1, x2c = x2;
        if (t + 1 < T_LEN) {
            x1 = (float)px1[(size_t)(t + 1) * N3];
            x2 = (float)px2[(size_t)(t + 1) * N3];
        }

        // ---- phase 1: z,r = sigmoid(a @ U{z,r} + x)   (all 8 waves)
        {
            float acc0 = 0.f, acc1 = 0.f, acc2 = 0.f, acc3 = 0.f;
            #define S1(j, A,B,C,D) { \
                half8_t av = *(const half8_t*)(aH + (j)*8); \
                acc0 = fdot2f(H2(av,0), A, acc0); \
                acc1 = fdot2f(H2(av,1), B, acc1); \
                acc2 = fdot2f(H2(av,2), C, acc2); \
                acc3 = fdot2f(H2(av,3), D, acc3); }
            S1(0,  wa0,  wa1,  wa2,  wa3)   S1(1,  wa4,  wa5,  wa6,  wa7)
            S1(2,  wa8,  wa9,  wa10, wa11)  S1(3,  wa12, wa13, wa14, wa15)
            S1(4,  wa16, wa17, wa18, wa19)  S1(5,  wa20, wa21, wa22, wa23)
            S1(6,  wa24, wa25, wa26, wa27)  S1(7,  wa28, wa29, wa30, wa31)
            S1(8,  wa32, wa33, wa34, wa35)  S1(9,  wa36, wa37, wa38, wa39)
            S1(10, wa40, wa41, wa42, wa43)  S1(11, wa44, wa45, wa46, wa47)
            S1(12, wa48, wa49, wa50, wa51)  S1(13, wa52, wa53, wa54, wa55)
            S1(14, wa56, wa57, wa58, wa59)  S1(15, wa60, wa61, wa62, wa63)
            S1(16, wa64, wa65, wa66, wa67)  S1(17, wa68, wa69, wa70, wa71)
            S1(18, wa72, wa73, wa74, wa75)  S1(19, wa76, wa77, wa78, wa79)
            S1(20, wa80, wa81, wa82, wa83)  S1(21, wa84, wa85, wa86, wa87)
            S1(22, wa88, wa89, wa90, wa91)  S1(23, wa92, wa93, wa94, wa95)
            S1(24, wa96, wa97, wa98, wa99)  S1(25, wa100,wa101,wa102,wa103)
            S1(26, wa104,wa105,wa106,wa107) S1(27, wa108,wa109,wa110,wa111)
            S1(28, wa112,wa113,wa114,wa115) S1(29, wa116,wa117,wa118,wa119)
            S1(30, wa120,wa121,wa122,wa123) S1(31, wa124,wa125,wa126,wa127)
            #undef S1
            float sig = fast_sigmoid((acc0 + acc1) + (acc2 + acc3) + x1c);
            if (g == 0) zS[u]  = sig;
            else        raH[u] = (_Float16)(sig * aF[u]);     // r * a
        }
        __syncthreads();

        // ---- phase 2: h = tanh((r*a) @ Uh + x); a' = z*a + (1-z)*h
        {
            float b0 = 0.f, b1 = 0.f;
            const _Float16* rbase = raH + (kh << 7);
            #define S2(j, A,B,C,D) { \
                half8_t rv = *(const half8_t*)(rbase + (j)*8); \
                b0 = fdot2f(H2(rv,0), A, b0); \
                b1 = fdot2f(H2(rv,1), B, b1); \
                b0 = fdot2f(H2(rv,2), C, b0); \
                b1 = fdot2f(H2(rv,3), D, b1); }
            S2(0,  wb0,  wb1,  wb2,  wb3)   S2(1,  wb4,  wb5,  wb6,  wb7)
            S2(2,  wb8,  wb9,  wb10, wb11)  S2(3,  wb12, wb13, wb14, wb15)
            S2(4,  wb16, wb17, wb18, wb19)  S2(5,  wb20, wb21, wb22, wb23)
            S2(6,  wb24, wb25, wb26, wb27)  S2(7,  wb28, wb29, wb30, wb31)
            S2(8,  wb32, wb33, wb34, wb35)  S2(9,  wb36, wb37, wb38, wb39)
            S2(10, wb40, wb41, wb42, wb43)  S2(11, wb44, wb45, wb46, wb47)
            S2(12, wb48, wb49, wb50, wb51)  S2(13, wb52, wb53, wb54, wb55)
            S2(14, wb56, wb57, wb58, wb59)  S2(15, wb60, wb61, wb62, wb63)
            #undef S2
            float hs = b0 + b1;
            hs += __shfl_xor(hs, 1, 64);                       // combine K-halves
            if (kh == 0) {
                float h  = fast_tanh(hs + x2c);
                float z  = zS[hcol];
                float an = z * aF[hcol] + (1.0f - z) * h;
                aF[hcol] = an;
                aH[hcol] = (_Float16)an;
            }
        }
        __syncthreads();
    }

    if (tid < U_SZ) out[(size_t)b * U_SZ + tid] = aF[tid];
}

// ---------------------------------------------------------------------------
extern "C" void kernel_launch(void* const* d_in, const int* in_sizes, int n_in,
                              void* d_out, int out_size, void* d_ws, size_t ws_size,
                              hipStream_t stream)
{
    const float* X    = (const float*)d_in[0];   // (64,2048,256)
    const float* W    = (const float*)d_in[1];   // (256,768)
    const float* RK   = (const float*)d_in[2];   // (256,768)
    const float* bias = (const float*)d_in[3];   // (768,)
    _Float16* proj = (_Float16*)d_ws;            // 131072*768*2 = 201.3 MB

    proj_gemm<<<MT_M * NT_N, 256, 0, stream>>>(X, W, bias, proj);
    gru_scan<<<B_SZ, 512, 0, stream>>>(RK, proj, (float*)d_out);
}

// Round 7
// 3698.762 us; speedup vs baseline: 1.3212x; 1.0732x over previous
//
#include <hip/hip_runtime.h>

// ---------------------------------------------------------------------------
// MDGRU fused implementation, MI355X (gfx950)
//   B=64, T=2048, D=256, U=256, 3U=768
//   Kernel 1: proj[b][t][0:768] = X[b][t][:] @ kernel + bias   (f16 in d_ws)
//   Kernel 2: per-batch persistent GRU scan, ALL weights in named VGPRs.
//
//   Register-grant model (fits r1/r2/r4/r6 measurements exactly):
//     budget = 512 / (minBlocksPerCU * waves_per_block / 4),
//     where minBlocksPerCU = __launch_bounds__ 2nd arg, DEFAULT 2.
//   r1-r6 always (implicitly) requested 2 blocks/CU -> 128-reg cap -> the
//   192 weight regs were rematerialized from L2 every step (~450 VALU +
//   ~180 L2 loads/thread/step = the ~2400 excess cycles/step).
//   THIS ROUND: __launch_bounds__(512, 1) -> budget 256. Demand ~215.
//   Decisive check: VGPR_Count must read >= 200 (128 = model falsified).
// ---------------------------------------------------------------------------

typedef _Float16 half2_t __attribute__((ext_vector_type(2)));
typedef _Float16 half8_t __attribute__((ext_vector_type(8)));
typedef float    float4_t __attribute__((ext_vector_type(4)));

#define T_LEN 2048
#define B_SZ  64
#define D_IN  256
#define N3    768   // 3*U
#define U_SZ  256

// extract half2 p (p=0..3) from a half8
#define H2(v, p) __builtin_shufflevector((v), (v), 2*(p), 2*(p)+1)

__device__ __forceinline__ float fdot2f(half2_t a, half2_t b, float c) {
#if __has_builtin(__builtin_amdgcn_fdot2)
    return __builtin_amdgcn_fdot2(a, b, c, false);
#else
    return c + (float)a[0]*(float)b[0] + (float)a[1]*(float)b[1];
#endif
}

__device__ __forceinline__ float fast_sigmoid(float s) {
    return __builtin_amdgcn_rcpf(1.0f + __builtin_amdgcn_exp2f(-1.44269504f * s));
}
__device__ __forceinline__ float fast_tanh(float s) {
    return 1.0f - 2.0f * __builtin_amdgcn_rcpf(1.0f + __builtin_amdgcn_exp2f(2.88539008f * s));
}

// pack RK[2i][col], RK[2i+1][col] (stride N3 floats) into one half2
__device__ __forceinline__ half2_t ldw(const float* p) {
    half2_t h; h[0] = (_Float16)p[0]; h[1] = (_Float16)p[N3]; return h;
}

// ---------------------------------------------------------------------------
// Kernel 1: proj GEMM (unchanged, known-good: ~830 us).
// ---------------------------------------------------------------------------
#define GA_LD 264
#define NT_N  16          // 768/48
#define MT_M  2048        // 131072/64

__global__ __launch_bounds__(256) void proj_gemm(
    const float* __restrict__ X, const float* __restrict__ W,
    const float* __restrict__ bias, _Float16* __restrict__ proj)
{
    __shared__ __align__(16) _Float16 Ah[64 * GA_LD];   // [row][k]
    __shared__ __align__(16) _Float16 Wh[48 * GA_LD];   // [col][k]

    unsigned bid = blockIdx.x;
    unsigned idx = bid >> 3;
    unsigned mt  = (bid & 7) * (MT_M / 8) + (idx >> 4);
    unsigned nt  = idx & (NT_N - 1);
    int m0 = mt * 64, n0 = nt * 48;
    int tid = threadIdx.x;

    {
        int r = tid >> 6;
        int k = (tid & 63) * 4;
        #pragma unroll
        for (int i = 0; i < 16; ++i) {
            int row = i * 4 + r;
            float4_t v = *(const float4_t*)(X + (size_t)(m0 + row) * D_IN + k);
            _Float16* p = Ah + row * GA_LD + k;
            p[0] = (_Float16)v.x; p[1] = (_Float16)v.y;
            p[2] = (_Float16)v.z; p[3] = (_Float16)v.w;
        }
    }
    {
        int c  = tid & 63;
        int kk = tid >> 6;
        if (c < 48) {
            #pragma unroll 4
            for (int i = 0; i < 64; ++i) {
                int krow = i * 4 + kk;
                Wh[c * GA_LD + krow] = (_Float16)W[(size_t)krow * N3 + n0 + c];
            }
        }
    }
    __syncthreads();

    int r0 = (tid >> 4) << 2;
    int c  = tid & 15;
    float acc[4][3];
    #pragma unroll
    for (int rr = 0; rr < 4; ++rr)
        #pragma unroll
        for (int cc = 0; cc < 3; ++cc) acc[rr][cc] = 0.0f;

    for (int j = 0; j < 32; ++j) {
        half8_t av[4], wv[3];
        #pragma unroll
        for (int rr = 0; rr < 4; ++rr)
            av[rr] = *(const half8_t*)(Ah + (r0 + rr) * GA_LD + j * 8);
        #pragma unroll
        for (int cc = 0; cc < 3; ++cc)
            wv[cc] = *(const half8_t*)(Wh + (c + 16 * cc) * GA_LD + j * 8);
        #pragma unroll
        for (int rr = 0; rr < 4; ++rr)
            #pragma unroll
            for (int cc = 0; cc < 3; ++cc) {
                acc[rr][cc] = fdot2f(H2(av[rr],0), H2(wv[cc],0), acc[rr][cc]);
                acc[rr][cc] = fdot2f(H2(av[rr],1), H2(wv[cc],1), acc[rr][cc]);
                acc[rr][cc] = fdot2f(H2(av[rr],2), H2(wv[cc],2), acc[rr][cc]);
                acc[rr][cc] = fdot2f(H2(av[rr],3), H2(wv[cc],3), acc[rr][cc]);
            }
    }

    float bv[3];
    #pragma unroll
    for (int cc = 0; cc < 3; ++cc) bv[cc] = bias[n0 + c + 16 * cc];
    #pragma unroll
    for (int rr = 0; rr < 4; ++rr)
        #pragma unroll
        for (int cc = 0; cc < 3; ++cc)
            proj[(size_t)(m0 + r0 + rr) * N3 + (n0 + c + 16 * cc)] =
                (_Float16)(acc[rr][cc] + bv[cc]);
}

// ---------------------------------------------------------------------------
// Kernel 2: persistent GRU scan, 64 blocks x 512 threads, minBlocks=1 ->
// 256-VGPR budget. Weights: 192 named half2 VGPRs per thread.
//   phase1: thread(g=tid>>8, u=tid&255) owns U{z|r}[:,u]      (wa0..wa127)
//   phase2: thread(hcol=tid>>1, kh=tid&1) owns K-half Uh[:,hcol] (wb0..wb63)
//           partials combined via __shfl_xor(1) (in-wave partner)
// ---------------------------------------------------------------------------
__global__ __launch_bounds__(512, 1)
void gru_scan(
    const float* __restrict__ RK, const _Float16* __restrict__ proj,
    float* __restrict__ out)
{
    __shared__ __align__(16) _Float16 aH[U_SZ];    // f16 mirror of state
    __shared__ __align__(16) _Float16 raH[U_SZ];   // f16 r*a
    __shared__ float zS[U_SZ];
    __shared__ float aF[U_SZ];                     // fp32 state (authoritative)

    const int b    = blockIdx.x;
    const int tid  = threadIdx.x;
    const int g    = tid >> 8;       // 0=z, 1=r (wave-uniform)
    const int u    = tid & 255;
    const int hcol = tid >> 1;       // phase-2 Uh column
    const int kh   = tid & 1;        // phase-2 K-half

    // ---- phase-1 weights: U{z|r}[:,u], 128 named half2 regs
    half2_t wa0,wa1,wa2,wa3,wa4,wa5,wa6,wa7,wa8,wa9,wa10,wa11,wa12,wa13,wa14,wa15,
            wa16,wa17,wa18,wa19,wa20,wa21,wa22,wa23,wa24,wa25,wa26,wa27,wa28,wa29,wa30,wa31,
            wa32,wa33,wa34,wa35,wa36,wa37,wa38,wa39,wa40,wa41,wa42,wa43,wa44,wa45,wa46,wa47,
            wa48,wa49,wa50,wa51,wa52,wa53,wa54,wa55,wa56,wa57,wa58,wa59,wa60,wa61,wa62,wa63,
            wa64,wa65,wa66,wa67,wa68,wa69,wa70,wa71,wa72,wa73,wa74,wa75,wa76,wa77,wa78,wa79,
            wa80,wa81,wa82,wa83,wa84,wa85,wa86,wa87,wa88,wa89,wa90,wa91,wa92,wa93,wa94,wa95,
            wa96,wa97,wa98,wa99,wa100,wa101,wa102,wa103,wa104,wa105,wa106,wa107,wa108,wa109,wa110,wa111,
            wa112,wa113,wa114,wa115,wa116,wa117,wa118,wa119,wa120,wa121,wa122,wa123,wa124,wa125,wa126,wa127;
    {
        const float* wp = RK + (size_t)(g << 8) + u;   // RK[k][g*256+u]
        #define LA(i) wa##i = ldw(wp + (size_t)(2*(i)) * N3);
        LA(0) LA(1) LA(2) LA(3) LA(4) LA(5) LA(6) LA(7)
        LA(8) LA(9) LA(10) LA(11) LA(12) LA(13) LA(14) LA(15)
        LA(16) LA(17) LA(18) LA(19) LA(20) LA(21) LA(22) LA(23)
        LA(24) LA(25) LA(26) LA(27) LA(28) LA(29) LA(30) LA(31)
        LA(32) LA(33) LA(34) LA(35) LA(36) LA(37) LA(38) LA(39)
        LA(40) LA(41) LA(42) LA(43) LA(44) LA(45) LA(46) LA(47)
        LA(48) LA(49) LA(50) LA(51) LA(52) LA(53) LA(54) LA(55)
        LA(56) LA(57) LA(58) LA(59) LA(60) LA(61) LA(62) LA(63)
        LA(64) LA(65) LA(66) LA(67) LA(68) LA(69) LA(70) LA(71)
        LA(72) LA(73) LA(74) LA(75) LA(76) LA(77) LA(78) LA(79)
        LA(80) LA(81) LA(82) LA(83) LA(84) LA(85) LA(86) LA(87)
        LA(88) LA(89) LA(90) LA(91) LA(92) LA(93) LA(94) LA(95)
        LA(96) LA(97) LA(98) LA(99) LA(100) LA(101) LA(102) LA(103)
        LA(104) LA(105) LA(106) LA(107) LA(108) LA(109) LA(110) LA(111)
        LA(112) LA(113) LA(114) LA(115) LA(116) LA(117) LA(118) LA(119)
        LA(120) LA(121) LA(122) LA(123) LA(124) LA(125) LA(126) LA(127)
        #undef LA
    }
    // ---- phase-2 weights: K-half of Uh[:,hcol], 64 named half2 regs
    half2_t wb0,wb1,wb2,wb3,wb4,wb5,wb6,wb7,wb8,wb9,wb10,wb11,wb12,wb13,wb14,wb15,
            wb16,wb17,wb18,wb19,wb20,wb21,wb22,wb23,wb24,wb25,wb26,wb27,wb28,wb29,wb30,wb31,
            wb32,wb33,wb34,wb35,wb36,wb37,wb38,wb39,wb40,wb41,wb42,wb43,wb44,wb45,wb46,wb47,
            wb48,wb49,wb50,wb51,wb52,wb53,wb54,wb55,wb56,wb57,wb58,wb59,wb60,wb61,wb62,wb63;
    {
        const float* wq = RK + (size_t)(kh * 128) * N3 + 512 + hcol;
        #define LB(i) wb##i = ldw(wq + (size_t)(2*(i)) * N3);
        LB(0) LB(1) LB(2) LB(3) LB(4) LB(5) LB(6) LB(7)
        LB(8) LB(9) LB(10) LB(11) LB(12) LB(13) LB(14) LB(15)
        LB(16) LB(17) LB(18) LB(19) LB(20) LB(21) LB(22) LB(23)
        LB(24) LB(25) LB(26) LB(27) LB(28) LB(29) LB(30) LB(31)
        LB(32) LB(33) LB(34) LB(35) LB(36) LB(37) LB(38) LB(39)
        LB(40) LB(41) LB(42) LB(43) LB(44) LB(45) LB(46) LB(47)
        LB(48) LB(49) LB(50) LB(51) LB(52) LB(53) LB(54) LB(55)
        LB(56) LB(57) LB(58) LB(59) LB(60) LB(61) LB(62) LB(63)
        #undef LB
    }

    if (tid < U_SZ) { aF[tid] = 0.0f; aH[tid] = (_Float16)0.0f; }

    // x streams: phase1 proj[b][t][g*256+u], phase2 proj[b][t][512+hcol]
    const _Float16* px1 = proj + ((size_t)b * T_LEN) * N3 + (g << 8) + u;
    const _Float16* px2 = proj + ((size_t)b * T_LEN) * N3 + 512 + hcol;
    float x1 = (float)px1[0];
    float x2 = (float)px2[0];
    __syncthreads();

    for (int t = 0; t < T_LEN; ++t) {
        const float x1c = x1, x2c = x2;
        if (t + 1 < T_LEN) {
            x1 = (float)px1[(size_t)(t + 1) * N3];
            x2 = (float)px2[(size_t)(t + 1) * N3];
        }

        // ---- phase 1: z,r = sigmoid(a @ U{z,r} + x)   (all 8 waves)
        {
            float acc0 = 0.f, acc1 = 0.f, acc2 = 0.f, acc3 = 0.f;
            #define S1(j, A,B,C,D) { \
                half8_t av = *(const half8_t*)(aH + (j)*8); \
                acc0 = fdot2f(H2(av,0), A, acc0); \
                acc1 = fdot2f(H2(av,1), B, acc1); \
                acc2 = fdot2f(H2(av,2), C, acc2); \
                acc3 = fdot2f(H2(av,3), D, acc3); }
            S1(0,  wa0,  wa1,  wa2,  wa3)   S1(1,  wa4,  wa5,  wa6,  wa7)
            S1(2,  wa8,  wa9,  wa10, wa11)  S1(3,  wa12, wa13, wa14, wa15)
            S1(4,  wa16, wa17, wa18, wa19)  S1(5,  wa20, wa21, wa22, wa23)
            S1(6,  wa24, wa25, wa26, wa27)  S1(7,  wa28, wa29, wa30, wa31)
            S1(8,  wa32, wa33, wa34, wa35)  S1(9,  wa36, wa37, wa38, wa39)
            S1(10, wa40, wa41, wa42, wa43)  S1(11, wa44, wa45, wa46, wa47)
            S1(12, wa48, wa49, wa50, wa51)  S1(13, wa52, wa53, wa54, wa55)
            S1(14, wa56, wa57, wa58, wa59)  S1(15, wa60, wa61, wa62, wa63)
            S1(16, wa64, wa65, wa66, wa67)  S1(17, wa68, wa69, wa70, wa71)
            S1(18, wa72, wa73, wa74, wa75)  S1(19, wa76, wa77, wa78, wa79)
            S1(20, wa80, wa81, wa82, wa83)  S1(21, wa84, wa85, wa86, wa87)
            S1(22, wa88, wa89, wa90, wa91)  S1(23, wa92, wa93, wa94, wa95)
            S1(24, wa96, wa97, wa98, wa99)  S1(25, wa100,wa101,wa102,wa103)
            S1(26, wa104,wa105,wa106,wa107) S1(27, wa108,wa109,wa110,wa111)
            S1(28, wa112,wa113,wa114,wa115) S1(29, wa116,wa117,wa118,wa119)
            S1(30, wa120,wa121,wa122,wa123) S1(31, wa124,wa125,wa126,wa127)
            #undef S1
            float sig = fast_sigmoid((acc0 + acc1) + (acc2 + acc3) + x1c);
            if (g == 0) zS[u]  = sig;
            else        raH[u] = (_Float16)(sig * aF[u]);     // r * a
        }
        __syncthreads();

        // ---- phase 2: h = tanh((r*a) @ Uh + x); a' = z*a + (1-z)*h
        {
            float b0 = 0.f, b1 = 0.f;
            const _Float16* rbase = raH + (kh << 7);
            #define S2(j, A,B,C,D) { \
                half8_t rv = *(const half8_t*)(rbase + (j)*8); \
                b0 = fdot2f(H2(rv,0), A, b0); \
                b1 = fdot2f(H2(rv,1), B, b1); \
                b0 = fdot2f(H2(rv,2), C, b0); \
                b1 = fdot2f(H2(rv,3), D, b1); }
            S2(0,  wb0,  wb1,  wb2,  wb3)   S2(1,  wb4,  wb5,  wb6,  wb7)
            S2(2,  wb8,  wb9,  wb10, wb11)  S2(3,  wb12, wb13, wb14, wb15)
            S2(4,  wb16, wb17, wb18, wb19)  S2(5,  wb20, wb21, wb22, wb23)
            S2(6,  wb24, wb25, wb26, wb27)  S2(7,  wb28, wb29, wb30, wb31)
            S2(8,  wb32, wb33, wb34, wb35)  S2(9,  wb36, wb37, wb38, wb39)
            S2(10, wb40, wb41, wb42, wb43)  S2(11, wb44, wb45, wb46, wb47)
            S2(12, wb48, wb49, wb50, wb51)  S2(13, wb52, wb53, wb54, wb55)
            S2(14, wb56, wb57, wb58, wb59)  S2(15, wb60, wb61, wb62, wb63)
            #undef S2
            float hs = b0 + b1;
            hs += __shfl_xor(hs, 1, 64);                       // combine K-halves
            if (kh == 0) {
                float h  = fast_tanh(hs + x2c);
                float z  = zS[hcol];
                float an = z * aF[hcol] + (1.0f - z) * h;
                aF[hcol] = an;
                aH[hcol] = (_Float16)an;
            }
        }
        __syncthreads();
    }

    if (tid < U_SZ) out[(size_t)b * U_SZ + tid] = aF[tid];
}

// ---------------------------------------------------------------------------
extern "C" void kernel_launch(void* const* d_in, const int* in_sizes, int n_in,
                              void* d_out, int out_size, void* d_ws, size_t ws_size,
                              hipStream_t stream)
{
    const float* X    = (const float*)d_in[0];   // (64,2048,256)
    const float* W    = (const float*)d_in[1];   // (256,768)
    const float* RK   = (const float*)d_in[2];   // (256,768)
    const float* bias = (const float*)d_in[3];   // (768,)
    _Float16* proj = (_Float16*)d_ws;            // 131072*768*2 = 201.3 MB

    proj_gemm<<<MT_M * NT_N, 256, 0, stream>>>(X, W, bias, proj);
    gru_scan<<<B_SZ, 512, 0, stream>>>(RK, proj, (float*)d_out);
}